// Round 3
// baseline (308.847 us; speedup 1.0000x reference)
//
#include <hip/hip_runtime.h>
#include <hip/hip_bf16.h>

typedef __attribute__((ext_vector_type(8))) short bf16x8;
typedef __attribute__((ext_vector_type(16))) float f32x16;
typedef __attribute__((ext_vector_type(4))) float f32x4;
typedef __attribute__((ext_vector_type(4))) unsigned int uint4v;
typedef unsigned short ushort_t;
typedef unsigned int uint_t;

#define N_NODES 16384
#define HD 128
#define NOUT 384
#define PART_ELEMS 6291456    // 16384*384
// packed B: pk[it][g][c][oct][l31][j]  it:0..129 (128,129 = U1,U2 tails)
//   byte offset = ((it*12+g)*16 + c*2 + oct)*512 + l31*16 + j*2 ; per-it = 98304 B

static __device__ __forceinline__ ushort_t f2bf(float f) {
  __hip_bfloat16 b = __float2bfloat16(f);
  return *reinterpret_cast<ushort_t*>(&b);
}

// ---------------- fused prep (384 threads/block) — unchanged ----------------
__global__ void prep_all(const float* __restrict__ A, const float* __restrict__ U1,
                         const float* __restrict__ U2, const float* __restrict__ nh,
                         ushort_t* __restrict__ pk, ushort_t* __restrict__ h1,
                         ushort_t* __restrict__ h2, float* __restrict__ h1tf) {
  __shared__ __align__(16) char smem[49152];
  const int b = blockIdx.x;
  const int t = threadIdx.x;

  if (b < 260) {
    short* spk = reinterpret_cast<short*>(smem);
    const int half = b & 1;
    const int gg = t >> 5, ll = t & 31;
    if (b < 256) {
      const int it = b >> 1;
      const size_t krow0 = (size_t)it * 128 + half * 64;
#pragma unroll 4
      for (int kl = 0; kl < 64; ++kl) {
        float v = A[(krow0 + kl) * NOUT + t];
        int cl = kl >> 4, oc = (kl >> 3) & 1, j = kl & 7;
        spk[(gg * 8 + cl * 2 + oc) * 256 + ll * 8 + j] = f2bf(v);
      }
    } else {
      const int u = (b - 256) >> 1;
      const float* U = u ? U2 : U1;
#pragma unroll 4
      for (int kl = 0; kl < 64; ++kl) {
        float v = U[(size_t)t * HD + half * 64 + kl];
        int cl = kl >> 4, oc = (kl >> 3) & 1, j = kl & 7;
        spk[(gg * 8 + cl * 2 + oc) * 256 + ll * 8 + j] = f2bf(v);
      }
    }
    __syncthreads();
    const int it_out = (b < 256) ? (b >> 1) : (128 + ((b - 256) >> 1));
    const int f = t * 64;
    const int g = f >> 11;
    const int inner = f & 2047;
    ushort_t* dst = pk + (size_t)it_out * 49152 + g * 4096 + half * 2048 + inner;
    const uint4* src = reinterpret_cast<const uint4*>(spk + f);
    uint4* d4 = reinterpret_cast<uint4*>(dst);
#pragma unroll
    for (int q = 0; q < 8; ++q) d4[q] = src[q];
  } else {
    if (t < 256) {
      float (*sm)[65] = reinterpret_cast<float(*)[65]>(smem);
      const int g = b - 260;            // 0..511
      const int mt = g & 255, jt = g >> 8;
      const int tx = t & 63, ty = t >> 6;
      const int m0 = mt * 64, j0 = jt * 64;
#pragma unroll
      for (int s = 0; s < 16; ++s) {
        int mm = ty + s * 4;
        float f1 = nh[(size_t)(m0 + mm) * 256 + j0 + tx];
        float f2 = nh[(size_t)(m0 + mm) * 256 + 128 + j0 + tx];
        h1[(size_t)(m0 + mm) * HD + j0 + tx] = f2bf(f1);
        h2[(size_t)(m0 + mm) * HD + j0 + tx] = f2bf(f2);
        sm[mm][tx] = f1;
      }
      __syncthreads();
#pragma unroll
      for (int s = 0; s < 16; ++s) {
        int jj = ty + s * 4;
        h1tf[(size_t)(j0 + jj) * N_NODES + m0 + tx] = sm[tx][jj];   // f32 transposed h1
      }
    }
  }
}

// ---------------- main GEMM: LDS-staged B slices (2-phase) + swapped-operand acc ----
// Per slice it, the block's 16 KB of pk (2 g-groups) is staged ONCE into LDS via
// global_load_lds (async DMA, no VGPR round-trip), double-buffered, one barrier/slice.
// This cuts L2->CU traffic 4x vs each wave loading its own copy (4 wm-waves share a
// g-group; L1 can't hold the stream). ds_reads are linear 1024B/instr -> conflict-free.
// accT[n,m] per lane: col(lane&31)=m-local, row(reg)=n-local.
// P^T = sum_c mfma(A=bb[c], B=h2u[ms][c]); acc[ms][r] += h1[m(lane), it] * P[r].
// Wave tile 64m x 32n. Block = 8 waves (4wm x 2wn) = 256m x 64n.
// grid = 64 Mt x 6 Nt x 2 ks = 768 blocks -> exactly 3 balanced rounds at 1 block/CU.
#define PK_STEP 98304

__global__ __launch_bounds__(512, 2)
void gemm_kernel(const ushort_t* __restrict__ pk, const ushort_t* __restrict__ h1bf,
                 const ushort_t* __restrict__ h2bf, const float* __restrict__ h1tf,
                 const float* __restrict__ u2b, float* __restrict__ part) {
  __shared__ __align__(16) char ldsb[2][16384];

  const int tid = threadIdx.x;
  const int bid = blockIdx.x;
  // XCD-clustering swizzle (bijective: 768 = 8*96): each XCD sees <=2 (Nt,ks) slabs.
  const int v  = (bid & 7) * 96 + (bid >> 3);
  const int Mt = v & 63;
  const int q  = v >> 6;        // 0..11
  const int Nt = q >> 1;
  const int ks = q & 1;

  const int lane = tid & 63, wv = tid >> 6;
  const int l31 = lane & 31, oct = lane >> 5;
  const int wm = wv >> 1, wn = wv & 1;          // 4m x 2n wave grid
  const int mbase = Mt * 256 + wm * 64;
  const int n0w = Nt * 64 + wn * 32;
  const int g0 = Nt * 2;                        // first 32-col group staged by this block

  // resident h2 fragments (used as MFMA B-operand): rows mbase+ms*32+l31
  uint4v h2u[2][8];
#pragma unroll
  for (int ms = 0; ms < 2; ++ms) {
    const ushort_t* hp = h2bf + (size_t)(mbase + ms * 32 + l31) * HD + oct * 8;
#pragma unroll
    for (int c = 0; c < 8; ++c)
      h2u[ms][c] = *reinterpret_cast<const uint4v*>(hp + c * 16);
  }

  // acc init (transposed layout): acc[ms][r] = out[mbase+ms*32+l31][n0w+(r&3)+8*(r>>2)+4*oct]
  f32x16 acc[2];
  if (ks) {
#pragma unroll
    for (int qq = 0; qq < 4; ++qq) {
      f32x4 bq = *reinterpret_cast<const f32x4*>(u2b + n0w + 8 * qq + 4 * oct);
#pragma unroll
      for (int j = 0; j < 4; ++j) { acc[0][qq * 4 + j] = bq[j]; acc[1][qq * 4 + j] = bq[j]; }
    }
  } else {
    acc[0] = (f32x16)(0.0f);
    acc[1] = (f32x16)(0.0f);
  }

  const int it0 = ks ? 65 : 0;
  const int it1 = ks ? 128 : 65;

  // per-block slice base: 16 KB contiguous starting at g0*8192
  const char* pkbase = reinterpret_cast<const char*>(pk) + (size_t)g0 * 8192;
  // staging split: wave wv covers LDS [wv*1024, +1024) in each 8 KB half
  const int stg = wv * 1024 + lane * 16;

  const float* ph1 = h1tf + (size_t)it0 * N_NODES + mbase + l31;
  const f32x16 vz = (f32x16)(0.0f);

  // prologue: stage slice it0 into buffer 0; preload h1 scalars for it0
  {
    const char* s = pkbase + (size_t)it0 * PK_STEP;
    __builtin_amdgcn_global_load_lds((const uint_t*)(s + stg),
                                     (uint_t*)(&ldsb[0][wv * 1024]), 16, 0, 0);
    __builtin_amdgcn_global_load_lds((const uint_t*)(s + stg + 8192),
                                     (uint_t*)(&ldsb[0][wv * 1024 + 8192]), 16, 0, 0);
  }
  float s0n = ph1[0], s1n = ph1[32];
  ph1 += N_NODES;
  asm volatile("s_waitcnt vmcnt(0)" ::: "memory");
  __syncthreads();

  int cur = 0;
  const char* ldrd_base0 = &ldsb[0][wn * 8192 + oct * 512 + l31 * 16];
  const char* ldrd_base1 = &ldsb[1][wn * 8192 + oct * 512 + l31 * 16];

  for (int it = it0; it < it1; ++it) {
    // async stage of slice it+1 into the other buffer (slice it1 staged harmlessly)
    {
      const char* s = pkbase + (size_t)(it + 1) * PK_STEP;
      char* d = &ldsb[cur ^ 1][wv * 1024];
      __builtin_amdgcn_global_load_lds((const uint_t*)(s + stg), (uint_t*)d, 16, 0, 0);
      __builtin_amdgcn_global_load_lds((const uint_t*)(s + stg + 8192),
                                       (uint_t*)(d + 8192), 16, 0, 0);
    }
    const float s0c = s0n, s1c = s1n;
    s0n = ph1[0]; s1n = ph1[32];      // prefetch next (last-iter read is benign garbage)
    ph1 += N_NODES;

    const char* lb = cur ? ldrd_base1 : ldrd_base0;
    uint4v bb[8];
#pragma unroll
    for (int c = 0; c < 8; ++c)
      bb[c] = *reinterpret_cast<const uint4v*>(lb + c * 1024);

    f32x16 P0 = vz, P1 = vz;
#pragma unroll
    for (int c = 0; c < 8; ++c) {
      bf16x8 bfr = __builtin_bit_cast(bf16x8, bb[c]);
      P0 = __builtin_amdgcn_mfma_f32_32x32x16_bf16(
          bfr, __builtin_bit_cast(bf16x8, h2u[0][c]), P0, 0, 0, 0);
      P1 = __builtin_amdgcn_mfma_f32_32x32x16_bf16(
          bfr, __builtin_bit_cast(bf16x8, h2u[1][c]), P1, 0, 0, 0);
    }
#pragma unroll
    for (int r = 0; r < 16; ++r) {
      acc[0][r] += s0c * P0[r];
      acc[1][r] += s1c * P1[r];
    }

    asm volatile("s_waitcnt vmcnt(0)" ::: "memory");   // stage of it+1 landed
    __syncthreads();
    cur ^= 1;
  }

  if (ks) {
    // U1 tail (it=128): accT += mfma(A=bb, B=h1 fragment)  — one-time global loads
    const char* bt = reinterpret_cast<const char*>(pk) +
                     (size_t)128 * PK_STEP + (size_t)((g0 + wn) * 16 + oct) * 512 +
                     (size_t)l31 * 16;
#pragma unroll
    for (int c = 0; c < 8; ++c) {
      bf16x8 bfr = __builtin_bit_cast(bf16x8, *reinterpret_cast<const uint4v*>(bt + c * 1024));
#pragma unroll
      for (int ms = 0; ms < 2; ++ms) {
        bf16x8 a = *reinterpret_cast<const bf16x8*>(
            h1bf + (size_t)(mbase + ms * 32 + l31) * HD + c * 16 + oct * 8);
        acc[ms] = __builtin_amdgcn_mfma_f32_32x32x16_bf16(bfr, a, acc[ms], 0, 0, 0);
      }
    }
    // U2 tail (it=129): accT += mfma(A=bb, B=h2u resident)
    const char* bt2 = bt + PK_STEP;
#pragma unroll
    for (int c = 0; c < 8; ++c) {
      bf16x8 bfr = __builtin_bit_cast(bf16x8, *reinterpret_cast<const uint4v*>(bt2 + c * 1024));
#pragma unroll
      for (int ms = 0; ms < 2; ++ms) {
        acc[ms] = __builtin_amdgcn_mfma_f32_32x32x16_bf16(
            bfr, __builtin_bit_cast(bf16x8, h2u[ms][c]), acc[ms], 0, 0, 0);
      }
    }
  }

  // epilogue: transposed regs regroup into aligned f32x4 row-chunks of out.
  // acc[ms][4q+j] -> out[mbase+ms*32+l31][n0w + 8q + 4*oct + j]
  float* my = part + (size_t)ks * PART_ELEMS;
#pragma unroll
  for (int ms = 0; ms < 2; ++ms) {
    float* rowp = my + (size_t)(mbase + ms * 32 + l31) * NOUT + n0w + 4 * oct;
#pragma unroll
    for (int qq = 0; qq < 4; ++qq) {
      f32x4 o;
      o[0] = acc[ms][qq * 4 + 0];
      o[1] = acc[ms][qq * 4 + 1];
      o[2] = acc[ms][qq * 4 + 2];
      o[3] = acc[ms][qq * 4 + 3];
      *reinterpret_cast<f32x4*>(rowp + 8 * qq) = o;
    }
  }
}

// ---------------- reduce: out = P0 + P1 (bias already in P1) ----------------
__global__ void reduce2(const float* __restrict__ part, float* __restrict__ out) {
  int i = blockIdx.x * 256 + threadIdx.x;          // 1,572,864 float4s
  float4 a = reinterpret_cast<const float4*>(part)[i];
  float4 b = reinterpret_cast<const float4*>(part + PART_ELEMS)[i];
  float4 o;
  o.x = a.x + b.x; o.y = a.y + b.y; o.z = a.z + b.z; o.w = a.w + b.w;
  reinterpret_cast<float4*>(out)[i] = o;
}

extern "C" void kernel_launch(void* const* d_in, const int* in_sizes, int n_in,
                              void* d_out, int out_size, void* d_ws, size_t ws_size,
                              hipStream_t stream) {
  const float* nh  = (const float*)d_in[0];   // (16384, 2, 128)
  const float* A   = (const float*)d_in[1];   // (128, 128, 384)
  const float* U1  = (const float*)d_in[2];   // (384, 128)
  const float* U2  = (const float*)d_in[3];   // (384, 128)
  const float* U2b = (const float*)d_in[4];   // (384,)

  char* ws = (char*)d_ws;
  ushort_t* pk   = (ushort_t*)(ws);                 // 130*98304    = 12,779,520 B
  ushort_t* h1bf = (ushort_t*)(ws + 12779520);      // 16384*128*2 =  4,194,304
  ushort_t* h2bf = (ushort_t*)(ws + 16973824);      //               4,194,304
  float*    h1tf = (float*)(ws + 21168128);         // 128*16384*4 =  8,388,608
  float*    part = (float*)(ws + 29556736);         // 2*25,165,824 = 50,331,648  (total ~79.9 MB)

  prep_all<<<dim3(772), 384, 0, stream>>>(A, U1, U2, nh, pk, h1bf, h2bf, h1tf);
  gemm_kernel<<<dim3(768), 512, 0, stream>>>(pk, h1bf, h2bf, h1tf, U2b, part);
  reduce2<<<dim3(6144), 256, 0, stream>>>(part, (float*)d_out);
}

// Round 4
// 308.702 us; speedup vs baseline: 1.0005x; 1.0005x over previous
//
#include <hip/hip_runtime.h>
#include <hip/hip_bf16.h>

typedef __attribute__((ext_vector_type(8))) short bf16x8;
typedef __attribute__((ext_vector_type(16))) float f32x16;
typedef __attribute__((ext_vector_type(4))) float f32x4;
typedef __attribute__((ext_vector_type(4))) unsigned int uint4v;
typedef unsigned short ushort_t;
typedef unsigned int uint_t;

#define N_NODES 16384
#define HD 128
#define NOUT 384
#define PART_ELEMS 6291456    // 16384*384
// packed B: pk[it][g][c][oct][l31][j]  it:0..129 (128,129 = U1,U2 tails)
//   byte offset = ((it*12+g)*16 + c*2 + oct)*512 + l31*16 + j*2 ; per-it = 98304 B

static __device__ __forceinline__ ushort_t f2bf(float f) {
  __hip_bfloat16 b = __float2bfloat16(f);
  return *reinterpret_cast<ushort_t*>(&b);
}

// ---------------- fused prep (384 threads/block) — unchanged ----------------
__global__ void prep_all(const float* __restrict__ A, const float* __restrict__ U1,
                         const float* __restrict__ U2, const float* __restrict__ nh,
                         ushort_t* __restrict__ pk, ushort_t* __restrict__ h1,
                         ushort_t* __restrict__ h2, float* __restrict__ h1tf) {
  __shared__ __align__(16) char smem[49152];
  const int b = blockIdx.x;
  const int t = threadIdx.x;

  if (b < 260) {
    short* spk = reinterpret_cast<short*>(smem);
    const int half = b & 1;
    const int gg = t >> 5, ll = t & 31;
    if (b < 256) {
      const int it = b >> 1;
      const size_t krow0 = (size_t)it * 128 + half * 64;
#pragma unroll 4
      for (int kl = 0; kl < 64; ++kl) {
        float v = A[(krow0 + kl) * NOUT + t];
        int cl = kl >> 4, oc = (kl >> 3) & 1, j = kl & 7;
        spk[(gg * 8 + cl * 2 + oc) * 256 + ll * 8 + j] = f2bf(v);
      }
    } else {
      const int u = (b - 256) >> 1;
      const float* U = u ? U2 : U1;
#pragma unroll 4
      for (int kl = 0; kl < 64; ++kl) {
        float v = U[(size_t)t * HD + half * 64 + kl];
        int cl = kl >> 4, oc = (kl >> 3) & 1, j = kl & 7;
        spk[(gg * 8 + cl * 2 + oc) * 256 + ll * 8 + j] = f2bf(v);
      }
    }
    __syncthreads();
    const int it_out = (b < 256) ? (b >> 1) : (128 + ((b - 256) >> 1));
    const int f = t * 64;
    const int g = f >> 11;
    const int inner = f & 2047;
    ushort_t* dst = pk + (size_t)it_out * 49152 + g * 4096 + half * 2048 + inner;
    const uint4* src = reinterpret_cast<const uint4*>(spk + f);
    uint4* d4 = reinterpret_cast<uint4*>(dst);
#pragma unroll
    for (int q = 0; q < 8; ++q) d4[q] = src[q];
  } else {
    if (t < 256) {
      float (*sm)[65] = reinterpret_cast<float(*)[65]>(smem);
      const int g = b - 260;            // 0..511
      const int mt = g & 255, jt = g >> 8;
      const int tx = t & 63, ty = t >> 6;
      const int m0 = mt * 64, j0 = jt * 64;
#pragma unroll
      for (int s = 0; s < 16; ++s) {
        int mm = ty + s * 4;
        float f1 = nh[(size_t)(m0 + mm) * 256 + j0 + tx];
        float f2 = nh[(size_t)(m0 + mm) * 256 + 128 + j0 + tx];
        h1[(size_t)(m0 + mm) * HD + j0 + tx] = f2bf(f1);
        h2[(size_t)(m0 + mm) * HD + j0 + tx] = f2bf(f2);
        sm[mm][tx] = f1;
      }
      __syncthreads();
#pragma unroll
      for (int s = 0; s < 16; ++s) {
        int jj = ty + s * 4;
        h1tf[(size_t)(j0 + jj) * N_NODES + m0 + tx] = sm[tx][jj];   // f32 transposed h1
      }
    }
  }
}

// ---------------- main GEMM: LDS ring-3, counted vmcnt, raw barriers (T3/T4) ----
// Slice payload staged per block: 16 KB pk (2 g-groups) + 1 KB h1 slab = 17408 B.
// Each wave issues EXACTLY 3 global_load_lds per slice (2 pk chunks + 1 h1, lanes<8),
// so the in-loop vmcnt stream is pure stage ops with exact counts:
//   end of slice it: s_waitcnt vmcnt(3) -> stage(it+1) landed, stage(it+2)'s 3 loads
//   remain in flight ACROSS the raw s_barrier (no __syncthreads drain).
// accT[n,m] per lane: col(lane&31)=m-local, row(reg)=n-local.
// P^T = sum_c mfma(A=bb[c], B=h2u[ms][c]); acc[ms][r] += h1[m(lane), it] * P[r].
// Wave tile 64m x 32n. Block = 8 waves (4wm x 2wn) = 256m x 64n.
// grid = 64 Mt x 6 Nt x 2 ks = 768 blocks -> exactly 3 balanced rounds at 1 block/CU.
#define PK_STEP 98304
#define SLICE_B 17408

#define STAGE(IT, R)                                                              \
  do {                                                                            \
    const char* s_ = pkbase + (size_t)(IT) * PK_STEP;                             \
    char* d_ = ldsb + (R) * SLICE_B;                                              \
    __builtin_amdgcn_global_load_lds((const uint_t*)(s_ + stg),                   \
                                     (uint_t*)(d_ + wv * 1024), 16, 0, 0);        \
    __builtin_amdgcn_global_load_lds((const uint_t*)(s_ + 8192 + stg),            \
                                     (uint_t*)(d_ + 8192 + wv * 1024), 16, 0, 0); \
    const int ith_ = (IT) < 128 ? (IT) : 127;                                     \
    const char* h_ = reinterpret_cast<const char*>(                               \
                         h1tf + (size_t)ith_ * N_NODES + Mt * 256) + wv * 128;    \
    if (lane < 8)                                                                 \
      __builtin_amdgcn_global_load_lds((const uint_t*)(h_ + lane * 16),           \
                                       (uint_t*)(d_ + 16384 + wv * 128), 16, 0, 0); \
  } while (0)

__global__ __launch_bounds__(512, 2)
void gemm_kernel(const ushort_t* __restrict__ pk, const ushort_t* __restrict__ h1bf,
                 const ushort_t* __restrict__ h2bf, const float* __restrict__ h1tf,
                 const float* __restrict__ u2b, float* __restrict__ part) {
  __shared__ __align__(16) char ldsb[3 * SLICE_B];

  const int tid = threadIdx.x;
  const int bid = blockIdx.x;
  // XCD-clustering swizzle (bijective: 768 = 8*96): each XCD sees <=2 (Nt,ks) slabs.
  const int v  = (bid & 7) * 96 + (bid >> 3);
  const int Mt = v & 63;
  const int q  = v >> 6;        // 0..11
  const int Nt = q >> 1;
  const int ks = q & 1;

  const int lane = tid & 63, wv = tid >> 6;
  const int l31 = lane & 31, oct = lane >> 5;
  const int wm = wv >> 1, wn = wv & 1;          // 4m x 2n wave grid
  const int mbase = Mt * 256 + wm * 64;
  const int n0w = Nt * 64 + wn * 32;
  const int g0 = Nt * 2;                        // first 32-col group staged by this block

  // resident h2 fragments (used as MFMA B-operand): rows mbase+ms*32+l31
  uint4v h2u[2][8];
#pragma unroll
  for (int ms = 0; ms < 2; ++ms) {
    const ushort_t* hp = h2bf + (size_t)(mbase + ms * 32 + l31) * HD + oct * 8;
#pragma unroll
    for (int c = 0; c < 8; ++c)
      h2u[ms][c] = *reinterpret_cast<const uint4v*>(hp + c * 16);
  }

  // acc init (transposed layout): acc[ms][r] = out[mbase+ms*32+l31][n0w+(r&3)+8*(r>>2)+4*oct]
  f32x16 acc[2];
  if (ks) {
#pragma unroll
    for (int qq = 0; qq < 4; ++qq) {
      f32x4 bq = *reinterpret_cast<const f32x4*>(u2b + n0w + 8 * qq + 4 * oct);
#pragma unroll
      for (int j = 0; j < 4; ++j) { acc[0][qq * 4 + j] = bq[j]; acc[1][qq * 4 + j] = bq[j]; }
    }
  } else {
    acc[0] = (f32x16)(0.0f);
    acc[1] = (f32x16)(0.0f);
  }

  const int it0 = ks ? 65 : 0;
  const int it1 = ks ? 128 : 65;

  // per-block slice base: 16 KB contiguous starting at g0*8192
  const char* pkbase = reinterpret_cast<const char*>(pk) + (size_t)g0 * 8192;
  const int stg = wv * 1024 + lane * 16;        // per-wave pk staging chunk

  const f32x16 vz = (f32x16)(0.0f);

  // prologue: stage slices it0 -> buf0, it0+1 -> buf1 (6 loads in flight/wave)
  STAGE(it0, 0);
  STAGE(it0 + 1, 1);
  asm volatile("s_waitcnt vmcnt(3)" ::: "memory");   // buf0 landed (also drains h2u/bias)
  __builtin_amdgcn_s_barrier();

  int r = 0, rs = 2;                                 // read buf, stage buf
  for (int it = it0; it < it1; ++it) {
    STAGE(it + 2, rs);                               // flies across the next barrier

    const char* lb = ldsb + r * SLICE_B;
    const float s0 = *reinterpret_cast<const float*>(lb + 16384 + (wm * 64 + l31) * 4);
    const float s1 = *reinterpret_cast<const float*>(lb + 16384 + (wm * 64 + 32 + l31) * 4);

    const char* bbase = lb + wn * 8192 + oct * 512 + l31 * 16;
    uint4v bb[8];
#pragma unroll
    for (int c = 0; c < 8; ++c)
      bb[c] = *reinterpret_cast<const uint4v*>(bbase + c * 1024);

    f32x16 P0 = vz, P1 = vz;
    __builtin_amdgcn_s_setprio(1);
#pragma unroll
    for (int c = 0; c < 8; ++c) {
      bf16x8 bfr = __builtin_bit_cast(bf16x8, bb[c]);
      P0 = __builtin_amdgcn_mfma_f32_32x32x16_bf16(
          bfr, __builtin_bit_cast(bf16x8, h2u[0][c]), P0, 0, 0, 0);
      P1 = __builtin_amdgcn_mfma_f32_32x32x16_bf16(
          bfr, __builtin_bit_cast(bf16x8, h2u[1][c]), P1, 0, 0, 0);
    }
    __builtin_amdgcn_s_setprio(0);
#pragma unroll
    for (int rr = 0; rr < 16; ++rr) {
      acc[0][rr] += s0 * P0[rr];
      acc[1][rr] += s1 * P1[rr];
    }

    // stage(it+1) landed; stage(it+2)'s 3 loads stay in flight across the barrier
    asm volatile("s_waitcnt vmcnt(3)" ::: "memory");
    __builtin_amdgcn_s_barrier();
    r = (r == 2) ? 0 : r + 1;
    rs = (rs == 2) ? 0 : rs + 1;
  }

  if (ks) {
    // U1 tail (it=128): accT += mfma(A=bb, B=h1 fragment)  — one-time global loads
    const char* bt = reinterpret_cast<const char*>(pk) +
                     (size_t)128 * PK_STEP + (size_t)((g0 + wn) * 16 + oct) * 512 +
                     (size_t)l31 * 16;
#pragma unroll
    for (int c = 0; c < 8; ++c) {
      bf16x8 bfr = __builtin_bit_cast(bf16x8, *reinterpret_cast<const uint4v*>(bt + c * 1024));
#pragma unroll
      for (int ms = 0; ms < 2; ++ms) {
        bf16x8 a = *reinterpret_cast<const bf16x8*>(
            h1bf + (size_t)(mbase + ms * 32 + l31) * HD + c * 16 + oct * 8);
        acc[ms] = __builtin_amdgcn_mfma_f32_32x32x16_bf16(bfr, a, acc[ms], 0, 0, 0);
      }
    }
    // U2 tail (it=129): accT += mfma(A=bb, B=h2u resident)
    const char* bt2 = bt + PK_STEP;
#pragma unroll
    for (int c = 0; c < 8; ++c) {
      bf16x8 bfr = __builtin_bit_cast(bf16x8, *reinterpret_cast<const uint4v*>(bt2 + c * 1024));
#pragma unroll
      for (int ms = 0; ms < 2; ++ms) {
        acc[ms] = __builtin_amdgcn_mfma_f32_32x32x16_bf16(
            bfr, __builtin_bit_cast(bf16x8, h2u[ms][c]), acc[ms], 0, 0, 0);
      }
    }
  }

  // epilogue: transposed regs regroup into aligned f32x4 row-chunks of out.
  // acc[ms][4q+j] -> out[mbase+ms*32+l31][n0w + 8q + 4*oct + j]
  float* my = part + (size_t)ks * PART_ELEMS;
#pragma unroll
  for (int ms = 0; ms < 2; ++ms) {
    float* rowp = my + (size_t)(mbase + ms * 32 + l31) * NOUT + n0w + 4 * oct;
#pragma unroll
    for (int qq = 0; qq < 4; ++qq) {
      f32x4 o;
      o[0] = acc[ms][qq * 4 + 0];
      o[1] = acc[ms][qq * 4 + 1];
      o[2] = acc[ms][qq * 4 + 2];
      o[3] = acc[ms][qq * 4 + 3];
      *reinterpret_cast<f32x4*>(rowp + 8 * qq) = o;
    }
  }
}

// ---------------- reduce: out = P0 + P1 (bias already in P1) ----------------
__global__ void reduce2(const float* __restrict__ part, float* __restrict__ out) {
  int i = blockIdx.x * 256 + threadIdx.x;          // 1,572,864 float4s
  float4 a = reinterpret_cast<const float4*>(part)[i];
  float4 b = reinterpret_cast<const float4*>(part + PART_ELEMS)[i];
  float4 o;
  o.x = a.x + b.x; o.y = a.y + b.y; o.z = a.z + b.z; o.w = a.w + b.w;
  reinterpret_cast<float4*>(out)[i] = o;
}

extern "C" void kernel_launch(void* const* d_in, const int* in_sizes, int n_in,
                              void* d_out, int out_size, void* d_ws, size_t ws_size,
                              hipStream_t stream) {
  const float* nh  = (const float*)d_in[0];   // (16384, 2, 128)
  const float* A   = (const float*)d_in[1];   // (128, 128, 384)
  const float* U1  = (const float*)d_in[2];   // (384, 128)
  const float* U2  = (const float*)d_in[3];   // (384, 128)
  const float* U2b = (const float*)d_in[4];   // (384,)

  char* ws = (char*)d_ws;
  ushort_t* pk   = (ushort_t*)(ws);                 // 130*98304    = 12,779,520 B
  ushort_t* h1bf = (ushort_t*)(ws + 12779520);      // 16384*128*2 =  4,194,304
  ushort_t* h2bf = (ushort_t*)(ws + 16973824);      //               4,194,304
  float*    h1tf = (float*)(ws + 21168128);         // 128*16384*4 =  8,388,608
  float*    part = (float*)(ws + 29556736);         // 2*25,165,824 = 50,331,648  (total ~79.9 MB)

  prep_all<<<dim3(772), 384, 0, stream>>>(A, U1, U2, nh, pk, h1bf, h2bf, h1tf);
  gemm_kernel<<<dim3(768), 512, 0, stream>>>(pk, h1bf, h2bf, h1tf, U2b, part);
  reduce2<<<dim3(6144), 256, 0, stream>>>(part, (float*)d_out);
}

// Round 5
// 308.581 us; speedup vs baseline: 1.0009x; 1.0004x over previous
//
#include <hip/hip_runtime.h>
#include <hip/hip_bf16.h>

typedef __attribute__((ext_vector_type(8))) short bf16x8;
typedef __attribute__((ext_vector_type(16))) float f32x16;
typedef __attribute__((ext_vector_type(4))) float f32x4;
typedef __attribute__((ext_vector_type(4))) unsigned int uint4v;
typedef unsigned short ushort_t;
typedef unsigned int uint_t;

#define N_NODES 16384
#define HD 128
#define NOUT 384
#define PART_ELEMS 6291456    // 16384*384
// packed B: pk[it][g][c][oct][l31][j]  it:0..129 (128,129 = U1,U2 tails)
//   byte offset = ((it*12+g)*16 + c*2 + oct)*512 + l31*16 + j*2 ; per-it = 98304 B

static __device__ __forceinline__ ushort_t f2bf(float f) {
  __hip_bfloat16 b = __float2bfloat16(f);
  return *reinterpret_cast<ushort_t*>(&b);
}

// ---------------- fused prep (384 threads/block) — unchanged ----------------
__global__ void prep_all(const float* __restrict__ A, const float* __restrict__ U1,
                         const float* __restrict__ U2, const float* __restrict__ nh,
                         ushort_t* __restrict__ pk, ushort_t* __restrict__ h1,
                         ushort_t* __restrict__ h2, float* __restrict__ h1tf) {
  __shared__ __align__(16) char smem[49152];
  const int b = blockIdx.x;
  const int t = threadIdx.x;

  if (b < 260) {
    short* spk = reinterpret_cast<short*>(smem);
    const int half = b & 1;
    const int gg = t >> 5, ll = t & 31;
    if (b < 256) {
      const int it = b >> 1;
      const size_t krow0 = (size_t)it * 128 + half * 64;
#pragma unroll 4
      for (int kl = 0; kl < 64; ++kl) {
        float v = A[(krow0 + kl) * NOUT + t];
        int cl = kl >> 4, oc = (kl >> 3) & 1, j = kl & 7;
        spk[(gg * 8 + cl * 2 + oc) * 256 + ll * 8 + j] = f2bf(v);
      }
    } else {
      const int u = (b - 256) >> 1;
      const float* U = u ? U2 : U1;
#pragma unroll 4
      for (int kl = 0; kl < 64; ++kl) {
        float v = U[(size_t)t * HD + half * 64 + kl];
        int cl = kl >> 4, oc = (kl >> 3) & 1, j = kl & 7;
        spk[(gg * 8 + cl * 2 + oc) * 256 + ll * 8 + j] = f2bf(v);
      }
    }
    __syncthreads();
    const int it_out = (b < 256) ? (b >> 1) : (128 + ((b - 256) >> 1));
    const int f = t * 64;
    const int g = f >> 11;
    const int inner = f & 2047;
    ushort_t* dst = pk + (size_t)it_out * 49152 + g * 4096 + half * 2048 + inner;
    const uint4* src = reinterpret_cast<const uint4*>(spk + f);
    uint4* d4 = reinterpret_cast<uint4*>(dst);
#pragma unroll
    for (int q = 0; q < 8; ++q) d4[q] = src[q];
  } else {
    if (t < 256) {
      float (*sm)[65] = reinterpret_cast<float(*)[65]>(smem);
      const int g = b - 260;            // 0..511
      const int mt = g & 255, jt = g >> 8;
      const int tx = t & 63, ty = t >> 6;
      const int m0 = mt * 64, j0 = jt * 64;
#pragma unroll
      for (int s = 0; s < 16; ++s) {
        int mm = ty + s * 4;
        float f1 = nh[(size_t)(m0 + mm) * 256 + j0 + tx];
        float f2 = nh[(size_t)(m0 + mm) * 256 + 128 + j0 + tx];
        h1[(size_t)(m0 + mm) * HD + j0 + tx] = f2bf(f1);
        h2[(size_t)(m0 + mm) * HD + j0 + tx] = f2bf(f2);
        sm[mm][tx] = f1;
      }
      __syncthreads();
#pragma unroll
      for (int s = 0; s < 16; ++s) {
        int jj = ty + s * 4;
        h1tf[(size_t)(j0 + jj) * N_NODES + m0 + tx] = sm[tx][jj];   // f32 transposed h1
      }
    }
  }
}

// ---------------- main GEMM: LDS ring-3 + 4 independent 4-deep MFMA chains/wave ----
// The R2/R3/R4 plateau at ~43% MfmaUtil across three different memory structures is
// the dependent-chain latency cap: 2x 8-deep chains/wave x 2 waves = 4 streams
// -> dependent-issue spacing 4x32.3 ~ 129 cy < mfma latency (~256 cy) -> ~50% cap.
// Fix: split each chain into two 4-deep halves (P0a/P0b, P1a/P1b) = 8 streams/SIMD
// -> spacing ~258 cy ~ latency -> cap ~100%. Memory/sync structure: R4's ring-3
// counted-vmcnt schedule (never drain vmcnt to 0 in-loop; raw s_barrier).
// accT[n,m] per lane: col(lane&31)=m-local, row(reg)=n-local.
// Wave tile 64m x 32n. Block = 8 waves (4wm x 2wn) = 256m x 64n.
// grid = 64 Mt x 6 Nt x 2 ks = 768 blocks -> exactly 3 balanced rounds at 1 block/CU.
#define PK_STEP 98304
#define SLICE_B 17408

#define STAGE(IT, R)                                                              \
  do {                                                                            \
    const char* s_ = pkbase + (size_t)(IT) * PK_STEP;                             \
    char* d_ = ldsb + (R) * SLICE_B;                                              \
    __builtin_amdgcn_global_load_lds((const uint_t*)(s_ + stg),                   \
                                     (uint_t*)(d_ + wv * 1024), 16, 0, 0);        \
    __builtin_amdgcn_global_load_lds((const uint_t*)(s_ + 8192 + stg),            \
                                     (uint_t*)(d_ + 8192 + wv * 1024), 16, 0, 0); \
    const int ith_ = (IT) < 128 ? (IT) : 127;                                     \
    const char* h_ = reinterpret_cast<const char*>(                               \
                         h1tf + (size_t)ith_ * N_NODES + Mt * 256) + wv * 128;    \
    if (lane < 8)                                                                 \
      __builtin_amdgcn_global_load_lds((const uint_t*)(h_ + lane * 16),           \
                                       (uint_t*)(d_ + 16384 + wv * 128), 16, 0, 0); \
  } while (0)

__global__ __launch_bounds__(512, 2)
void gemm_kernel(const ushort_t* __restrict__ pk, const ushort_t* __restrict__ h1bf,
                 const ushort_t* __restrict__ h2bf, const float* __restrict__ h1tf,
                 const float* __restrict__ u2b, float* __restrict__ part) {
  __shared__ __align__(16) char ldsb[3 * SLICE_B];

  const int tid = threadIdx.x;
  const int bid = blockIdx.x;
  // XCD-clustering swizzle (bijective: 768 = 8*96): each XCD sees <=2 (Nt,ks) slabs.
  const int v  = (bid & 7) * 96 + (bid >> 3);
  const int Mt = v & 63;
  const int q  = v >> 6;        // 0..11
  const int Nt = q >> 1;
  const int ks = q & 1;

  const int lane = tid & 63, wv = tid >> 6;
  const int l31 = lane & 31, oct = lane >> 5;
  const int wm = wv >> 1, wn = wv & 1;          // 4m x 2n wave grid
  const int mbase = Mt * 256 + wm * 64;
  const int n0w = Nt * 64 + wn * 32;
  const int g0 = Nt * 2;                        // first 32-col group staged by this block

  // resident h2 fragments (used as MFMA B-operand): rows mbase+ms*32+l31
  uint4v h2u[2][8];
#pragma unroll
  for (int ms = 0; ms < 2; ++ms) {
    const ushort_t* hp = h2bf + (size_t)(mbase + ms * 32 + l31) * HD + oct * 8;
#pragma unroll
    for (int c = 0; c < 8; ++c)
      h2u[ms][c] = *reinterpret_cast<const uint4v*>(hp + c * 16);
  }

  // acc init (transposed layout): acc[ms][r] = out[mbase+ms*32+l31][n0w+(r&3)+8*(r>>2)+4*oct]
  f32x16 acc[2];
  if (ks) {
#pragma unroll
    for (int qq = 0; qq < 4; ++qq) {
      f32x4 bq = *reinterpret_cast<const f32x4*>(u2b + n0w + 8 * qq + 4 * oct);
#pragma unroll
      for (int j = 0; j < 4; ++j) { acc[0][qq * 4 + j] = bq[j]; acc[1][qq * 4 + j] = bq[j]; }
    }
  } else {
    acc[0] = (f32x16)(0.0f);
    acc[1] = (f32x16)(0.0f);
  }

  const int it0 = ks ? 65 : 0;
  const int it1 = ks ? 128 : 65;

  // per-block slice base: 16 KB contiguous starting at g0*8192
  const char* pkbase = reinterpret_cast<const char*>(pk) + (size_t)g0 * 8192;
  const int stg = wv * 1024 + lane * 16;        // per-wave pk staging chunk

  const f32x16 vz = (f32x16)(0.0f);

  // prologue: stage slices it0 -> buf0, it0+1 -> buf1 (6 loads in flight/wave)
  STAGE(it0, 0);
  STAGE(it0 + 1, 1);
  asm volatile("s_waitcnt vmcnt(3)" ::: "memory");   // buf0 landed (also drains h2u/bias)
  __builtin_amdgcn_s_barrier();

  int r = 0, rs = 2;                                 // read buf, stage buf
  for (int it = it0; it < it1; ++it) {
    STAGE(it + 2, rs);                               // flies across the next barrier

    const char* lb = ldsb + r * SLICE_B;
    const float s0 = *reinterpret_cast<const float*>(lb + 16384 + (wm * 64 + l31) * 4);
    const float s1 = *reinterpret_cast<const float*>(lb + 16384 + (wm * 64 + 32 + l31) * 4);

    const char* bbase = lb + wn * 8192 + oct * 512 + l31 * 16;
    uint4v bb[8];
#pragma unroll
    for (int c = 0; c < 8; ++c)
      bb[c] = *reinterpret_cast<const uint4v*>(bbase + c * 1024);

    // 4 independent 4-deep chains: dependent reissue spacing = 4 mfma slots.
    f32x16 P0a = vz, P0b = vz, P1a = vz, P1b = vz;
    __builtin_amdgcn_s_setprio(1);
#pragma unroll
    for (int cc = 0; cc < 4; ++cc) {
      bf16x8 f0 = __builtin_bit_cast(bf16x8, bb[cc]);
      bf16x8 f1 = __builtin_bit_cast(bf16x8, bb[cc + 4]);
      P0a = __builtin_amdgcn_mfma_f32_32x32x16_bf16(
          f0, __builtin_bit_cast(bf16x8, h2u[0][cc]), P0a, 0, 0, 0);
      P1a = __builtin_amdgcn_mfma_f32_32x32x16_bf16(
          f0, __builtin_bit_cast(bf16x8, h2u[1][cc]), P1a, 0, 0, 0);
      P0b = __builtin_amdgcn_mfma_f32_32x32x16_bf16(
          f1, __builtin_bit_cast(bf16x8, h2u[0][cc + 4]), P0b, 0, 0, 0);
      P1b = __builtin_amdgcn_mfma_f32_32x32x16_bf16(
          f1, __builtin_bit_cast(bf16x8, h2u[1][cc + 4]), P1b, 0, 0, 0);
    }
    __builtin_amdgcn_s_setprio(0);
#pragma unroll
    for (int rr = 0; rr < 16; ++rr) {
      acc[0][rr] += s0 * (P0a[rr] + P0b[rr]);
      acc[1][rr] += s1 * (P1a[rr] + P1b[rr]);
    }

    // stage(it+1) landed; stage(it+2)'s 3 loads stay in flight across the barrier
    asm volatile("s_waitcnt vmcnt(3)" ::: "memory");
    __builtin_amdgcn_s_barrier();
    r = (r == 2) ? 0 : r + 1;
    rs = (rs == 2) ? 0 : rs + 1;
  }

  if (ks) {
    // U1 tail (it=128): accT += mfma(A=bb, B=h1 fragment)  — one-time global loads
    const char* bt = reinterpret_cast<const char*>(pk) +
                     (size_t)128 * PK_STEP + (size_t)((g0 + wn) * 16 + oct) * 512 +
                     (size_t)l31 * 16;
#pragma unroll
    for (int c = 0; c < 8; ++c) {
      bf16x8 bfr = __builtin_bit_cast(bf16x8, *reinterpret_cast<const uint4v*>(bt + c * 1024));
#pragma unroll
      for (int ms = 0; ms < 2; ++ms) {
        bf16x8 a = *reinterpret_cast<const bf16x8*>(
            h1bf + (size_t)(mbase + ms * 32 + l31) * HD + c * 16 + oct * 8);
        acc[ms] = __builtin_amdgcn_mfma_f32_32x32x16_bf16(bfr, a, acc[ms], 0, 0, 0);
      }
    }
    // U2 tail (it=129): accT += mfma(A=bb, B=h2u resident)
    const char* bt2 = bt + PK_STEP;
#pragma unroll
    for (int c = 0; c < 8; ++c) {
      bf16x8 bfr = __builtin_bit_cast(bf16x8, *reinterpret_cast<const uint4v*>(bt2 + c * 1024));
#pragma unroll
      for (int ms = 0; ms < 2; ++ms) {
        acc[ms] = __builtin_amdgcn_mfma_f32_32x32x16_bf16(
            bfr, __builtin_bit_cast(bf16x8, h2u[ms][c]), acc[ms], 0, 0, 0);
      }
    }
  }

  // epilogue: transposed regs regroup into aligned f32x4 row-chunks of out.
  // acc[ms][4q+j] -> out[mbase+ms*32+l31][n0w + 8q + 4*oct + j]
  float* my = part + (size_t)ks * PART_ELEMS;
#pragma unroll
  for (int ms = 0; ms < 2; ++ms) {
    float* rowp = my + (size_t)(mbase + ms * 32 + l31) * NOUT + n0w + 4 * oct;
#pragma unroll
    for (int qq = 0; qq < 4; ++qq) {
      f32x4 o;
      o[0] = acc[ms][qq * 4 + 0];
      o[1] = acc[ms][qq * 4 + 1];
      o[2] = acc[ms][qq * 4 + 2];
      o[3] = acc[ms][qq * 4 + 3];
      *reinterpret_cast<f32x4*>(rowp + 8 * qq) = o;
    }
  }
}

// ---------------- reduce: out = P0 + P1 (bias already in P1) ----------------
__global__ void reduce2(const float* __restrict__ part, float* __restrict__ out) {
  int i = blockIdx.x * 256 + threadIdx.x;          // 1,572,864 float4s
  float4 a = reinterpret_cast<const float4*>(part)[i];
  float4 b = reinterpret_cast<const float4*>(part + PART_ELEMS)[i];
  float4 o;
  o.x = a.x + b.x; o.y = a.y + b.y; o.z = a.z + b.z; o.w = a.w + b.w;
  reinterpret_cast<float4*>(out)[i] = o;
}

extern "C" void kernel_launch(void* const* d_in, const int* in_sizes, int n_in,
                              void* d_out, int out_size, void* d_ws, size_t ws_size,
                              hipStream_t stream) {
  const float* nh  = (const float*)d_in[0];   // (16384, 2, 128)
  const float* A   = (const float*)d_in[1];   // (128, 128, 384)
  const float* U1  = (const float*)d_in[2];   // (384, 128)
  const float* U2  = (const float*)d_in[3];   // (384, 128)
  const float* U2b = (const float*)d_in[4];   // (384,)

  char* ws = (char*)d_ws;
  ushort_t* pk   = (ushort_t*)(ws);                 // 130*98304    = 12,779,520 B
  ushort_t* h1bf = (ushort_t*)(ws + 12779520);      // 16384*128*2 =  4,194,304
  ushort_t* h2bf = (ushort_t*)(ws + 16973824);      //               4,194,304
  float*    h1tf = (float*)(ws + 21168128);         // 128*16384*4 =  8,388,608
  float*    part = (float*)(ws + 29556736);         // 2*25,165,824 = 50,331,648  (total ~79.9 MB)

  prep_all<<<dim3(772), 384, 0, stream>>>(A, U1, U2, nh, pk, h1bf, h2bf, h1tf);
  gemm_kernel<<<dim3(768), 512, 0, stream>>>(pk, h1bf, h2bf, h1tf, U2b, part);
  reduce2<<<dim3(6144), 256, 0, stream>>>(part, (float*)d_out);
}

// Round 6
// 292.185 us; speedup vs baseline: 1.0570x; 1.0561x over previous
//
#include <hip/hip_runtime.h>
#include <hip/hip_bf16.h>

typedef __attribute__((ext_vector_type(8))) short bf16x8;
typedef __attribute__((ext_vector_type(16))) float f32x16;
typedef __attribute__((ext_vector_type(4))) float f32x4;
typedef __attribute__((ext_vector_type(4))) unsigned int uint4v;
typedef unsigned short ushort_t;
typedef unsigned int uint_t;

#define N_NODES 16384
#define HD 128
#define NOUT 384
#define PART_ELEMS 6291456    // 16384*384
// packed B: pk[it][g][c][oct][l31][j]  it:0..129 (128,129 = U1,U2 tails)
//   byte offset = ((it*12+g)*16 + c*2 + oct)*512 + l31*16 + j*2 ; per-it = 98304 B

static __device__ __forceinline__ ushort_t f2bf(float f) {
  __hip_bfloat16 b = __float2bfloat16(f);
  return *reinterpret_cast<ushort_t*>(&b);
}

// ---------------- fused prep (384 threads/block) — unchanged ----------------
__global__ void prep_all(const float* __restrict__ A, const float* __restrict__ U1,
                         const float* __restrict__ U2, const float* __restrict__ nh,
                         ushort_t* __restrict__ pk, ushort_t* __restrict__ h1,
                         ushort_t* __restrict__ h2, float* __restrict__ h1tf) {
  __shared__ __align__(16) char smem[49152];
  const int b = blockIdx.x;
  const int t = threadIdx.x;

  if (b < 260) {
    short* spk = reinterpret_cast<short*>(smem);
    const int half = b & 1;
    const int gg = t >> 5, ll = t & 31;
    if (b < 256) {
      const int it = b >> 1;
      const size_t krow0 = (size_t)it * 128 + half * 64;
#pragma unroll 4
      for (int kl = 0; kl < 64; ++kl) {
        float v = A[(krow0 + kl) * NOUT + t];
        int cl = kl >> 4, oc = (kl >> 3) & 1, j = kl & 7;
        spk[(gg * 8 + cl * 2 + oc) * 256 + ll * 8 + j] = f2bf(v);
      }
    } else {
      const int u = (b - 256) >> 1;
      const float* U = u ? U2 : U1;
#pragma unroll 4
      for (int kl = 0; kl < 64; ++kl) {
        float v = U[(size_t)t * HD + half * 64 + kl];
        int cl = kl >> 4, oc = (kl >> 3) & 1, j = kl & 7;
        spk[(gg * 8 + cl * 2 + oc) * 256 + ll * 8 + j] = f2bf(v);
      }
    }
    __syncthreads();
    const int it_out = (b < 256) ? (b >> 1) : (128 + ((b - 256) >> 1));
    const int f = t * 64;
    const int g = f >> 11;
    const int inner = f & 2047;
    ushort_t* dst = pk + (size_t)it_out * 49152 + g * 4096 + half * 2048 + inner;
    const uint4* src = reinterpret_cast<const uint4*>(spk + f);
    uint4* d4 = reinterpret_cast<uint4*>(dst);
#pragma unroll
    for (int q = 0; q < 8; ++q) d4[q] = src[q];
  } else {
    if (t < 256) {
      float (*sm)[65] = reinterpret_cast<float(*)[65]>(smem);
      const int g = b - 260;            // 0..511
      const int mt = g & 255, jt = g >> 8;
      const int tx = t & 63, ty = t >> 6;
      const int m0 = mt * 64, j0 = jt * 64;
#pragma unroll
      for (int s = 0; s < 16; ++s) {
        int mm = ty + s * 4;
        float f1 = nh[(size_t)(m0 + mm) * 256 + j0 + tx];
        float f2 = nh[(size_t)(m0 + mm) * 256 + 128 + j0 + tx];
        h1[(size_t)(m0 + mm) * HD + j0 + tx] = f2bf(f1);
        h2[(size_t)(m0 + mm) * HD + j0 + tx] = f2bf(f2);
        sm[mm][tx] = f1;
      }
      __syncthreads();
#pragma unroll
      for (int s = 0; s < 16; ++s) {
        int jj = ty + s * 4;
        h1tf[(size_t)(j0 + jj) * N_NODES + m0 + tx] = sm[tx][jj];   // f32 transposed h1
      }
    }
  }
}

// ---------------- main GEMM: ring-3 LDS + reg-pipelined reads + deferred tail ----
// R2-R5 plateau at 43% MfmaUtil: per-slice fragment-data wait (lgkm queueing under
// 66 KB/CU/slice of LDS reads needed within ~100cy) + mfma-latency+tail serialization
// sit on every wave's critical path. Fix (software pipeline in registers):
//   (a) ds_read slice it+1's fragments DURING slice it's chain (full-slice slack);
//   (b) defer the scale-acc tail of slice it-1 into slice it (register-only by then).
// Per-slice path -> max(MFMA pipe ~1033cy, LDS pipe ~790cy) instead of their sum+waits.
// DMA ring-3 with counted vmcnt(3); one raw s_barrier per slice (certifies that ALL
// waves' stage(it+1) landed before any wave ds_reads buf[it+1] — vmcnt is per-wave).
// accT[n,m] per lane: col(lane&31)=m-local, row(reg)=n-local.
// Wave tile 64m x 32n. Block = 8 waves (4wm x 2wn) = 256m x 64n.
// grid = 64 Mt x 6 Nt x 2 ks = 768 blocks -> exactly 3 balanced rounds at 1 block/CU.
#define PK_STEP 98304
#define SLICE_B 17408

#define STAGE(IT, R)                                                              \
  do {                                                                            \
    const char* s_ = pkbase + (size_t)(IT) * PK_STEP;                             \
    char* d_ = ldsb + (R) * SLICE_B;                                              \
    __builtin_amdgcn_global_load_lds((const uint_t*)(s_ + stg),                   \
                                     (uint_t*)(d_ + wv * 1024), 16, 0, 0);        \
    __builtin_amdgcn_global_load_lds((const uint_t*)(s_ + 8192 + stg),            \
                                     (uint_t*)(d_ + 8192 + wv * 1024), 16, 0, 0); \
    const int ith_ = (IT) < 128 ? (IT) : 127;                                     \
    const char* h_ = reinterpret_cast<const char*>(                               \
                         h1tf + (size_t)ith_ * N_NODES + Mt * 256) + wv * 128;    \
    if (lane < 8)                                                                 \
      __builtin_amdgcn_global_load_lds((const uint_t*)(h_ + lane * 16),           \
                                       (uint_t*)(d_ + 16384 + wv * 128), 16, 0, 0); \
  } while (0)

#define READ_NEXT(BBN, SN0, SN1, RN)                                              \
  do {                                                                            \
    const char* lb_ = ldsb + (RN) * SLICE_B;                                      \
    const char* bb_ = lb_ + wn * 8192 + oct * 512 + l31 * 16;                     \
    _Pragma("unroll")                                                             \
    for (int c = 0; c < 8; ++c)                                                   \
      BBN[c] = *reinterpret_cast<const uint4v*>(bb_ + c * 1024);                  \
    SN0 = *reinterpret_cast<const float*>(lb_ + 16384 + (wm * 64 + l31) * 4);     \
    SN1 = *reinterpret_cast<const float*>(lb_ + 16384 + (wm * 64 + 32 + l31) * 4);\
  } while (0)

#define CHAIN(BBC, PC0, PC1)                                                      \
  do {                                                                            \
    PC0 = vz; PC1 = vz;                                                           \
    __builtin_amdgcn_s_setprio(1);                                                \
    _Pragma("unroll")                                                             \
    for (int c = 0; c < 8; ++c) {                                                 \
      bf16x8 f_ = __builtin_bit_cast(bf16x8, BBC[c]);                             \
      PC0 = __builtin_amdgcn_mfma_f32_32x32x16_bf16(                              \
          f_, __builtin_bit_cast(bf16x8, h2u[0][c]), PC0, 0, 0, 0);               \
      PC1 = __builtin_amdgcn_mfma_f32_32x32x16_bf16(                              \
          f_, __builtin_bit_cast(bf16x8, h2u[1][c]), PC1, 0, 0, 0);               \
    }                                                                             \
    __builtin_amdgcn_s_setprio(0);                                                \
  } while (0)

#define TAIL(S0_, S1_, PP0, PP1)                                                  \
  do {                                                                            \
    _Pragma("unroll")                                                             \
    for (int rr = 0; rr < 16; ++rr) {                                             \
      acc[0][rr] += (S0_) * PP0[rr];                                              \
      acc[1][rr] += (S1_) * PP1[rr];                                              \
    }                                                                             \
  } while (0)

__global__ __launch_bounds__(512, 2)
void gemm_kernel(const ushort_t* __restrict__ pk, const ushort_t* __restrict__ h1bf,
                 const ushort_t* __restrict__ h2bf, const float* __restrict__ h1tf,
                 const float* __restrict__ u2b, float* __restrict__ part) {
  __shared__ __align__(16) char ldsb[3 * SLICE_B];

  const int tid = threadIdx.x;
  const int bid = blockIdx.x;
  // XCD-clustering swizzle (bijective: 768 = 8*96): each XCD sees <=2 (Nt,ks) slabs.
  const int v  = (bid & 7) * 96 + (bid >> 3);
  const int Mt = v & 63;
  const int q  = v >> 6;        // 0..11
  const int Nt = q >> 1;
  const int ks = q & 1;

  const int lane = tid & 63, wv = tid >> 6;
  const int l31 = lane & 31, oct = lane >> 5;
  const int wm = wv >> 1, wn = wv & 1;          // 4m x 2n wave grid
  const int mbase = Mt * 256 + wm * 64;
  const int n0w = Nt * 64 + wn * 32;
  const int g0 = Nt * 2;                        // first 32-col group staged by this block

  // resident h2 fragments (used as MFMA B-operand): rows mbase+ms*32+l31
  uint4v h2u[2][8];
#pragma unroll
  for (int ms = 0; ms < 2; ++ms) {
    const ushort_t* hp = h2bf + (size_t)(mbase + ms * 32 + l31) * HD + oct * 8;
#pragma unroll
    for (int c = 0; c < 8; ++c)
      h2u[ms][c] = *reinterpret_cast<const uint4v*>(hp + c * 16);
  }

  // acc init (transposed layout): acc[ms][r] = out[mbase+ms*32+l31][n0w+(r&3)+8*(r>>2)+4*oct]
  f32x16 acc[2];
  if (ks) {
#pragma unroll
    for (int qq = 0; qq < 4; ++qq) {
      f32x4 bq = *reinterpret_cast<const f32x4*>(u2b + n0w + 8 * qq + 4 * oct);
#pragma unroll
      for (int j = 0; j < 4; ++j) { acc[0][qq * 4 + j] = bq[j]; acc[1][qq * 4 + j] = bq[j]; }
    }
  } else {
    acc[0] = (f32x16)(0.0f);
    acc[1] = (f32x16)(0.0f);
  }

  const int it0 = ks ? 65 : 0;
  const int it1 = ks ? 128 : 65;   // nit = 65 / 63, both odd

  // per-block slice base: 16 KB contiguous starting at g0*8192
  const char* pkbase = reinterpret_cast<const char*>(pk) + (size_t)g0 * 8192;
  const int stg = wv * 1024 + lane * 16;        // per-wave pk staging chunk

  const f32x16 vz = (f32x16)(0.0f);

  // prologue: stage it0 -> buf0, it0+1 -> buf1; read slice it0 into X registers
  STAGE(it0, 0);
  STAGE(it0 + 1, 1);
  asm volatile("s_waitcnt vmcnt(3)" ::: "memory");   // stage(it0) certified (this wave)
  __builtin_amdgcn_s_barrier();                      // ... for ALL waves
  uint4v bbX[8], bbY[8];
  f32x16 pX0, pX1, pY0 = vz, pY1 = vz;
  float sX0, sX1, sY0 = 0.0f, sY1 = 0.0f;            // zero => first (dummy) tail adds 0
  READ_NEXT(bbX, sX0, sX1, 0);                       // slice it0 fragments -> regs

  int rn = 1, rsb = 2;                               // ring idx: next-read buf, stage buf
  for (int it = it0; it < it1 - 1; it += 2) {
    // ---- even body: chain it (X), read it+1 (Y), tail it-1 (old Y) ----
    {
      const float t0 = sY0, t1 = sY1;
      STAGE(it + 2, rsb); rsb = (rsb == 2) ? 0 : rsb + 1;
      asm volatile("s_waitcnt vmcnt(3)" ::: "memory");  // stage(it+1) landed (this wave)
      __builtin_amdgcn_s_barrier();                     // ... all waves -> buf[it+1] valid
      READ_NEXT(bbY, sY0, sY1, rn); rn = (rn == 2) ? 0 : rn + 1;
      TAIL(t0, t1, pY0, pY1);
      CHAIN(bbX, pX0, pX1);
    }
    // ---- odd body: chain it+1 (Y), read it+2 (X), tail it (X) ----
    {
      const float t0 = sX0, t1 = sX1;
      STAGE(it + 3, rsb); rsb = (rsb == 2) ? 0 : rsb + 1;
      asm volatile("s_waitcnt vmcnt(3)" ::: "memory");
      __builtin_amdgcn_s_barrier();
      READ_NEXT(bbX, sX0, sX1, rn); rn = (rn == 2) ? 0 : rn + 1;
      TAIL(t0, t1, pX0, pX1);
      CHAIN(bbY, pY0, pY1);
    }
  }
  // last slice (even parity): it = it1-1. No next read needed.
  {
    STAGE(it1 + 1, rsb);                 // exists: 66 (ks=0) / 129 (ks=1); harmless
    asm volatile("s_waitcnt vmcnt(3)" ::: "memory");
    __builtin_amdgcn_s_barrier();
    TAIL(sY0, sY1, pY0, pY1);            // tail of it1-2
    CHAIN(bbX, pX0, pX1);                // chain of it1-1
    TAIL(sX0, sX1, pX0, pX1);            // final tail (compiler waits for pX)
  }

  if (ks) {
    // U1 tail (it=128): accT += mfma(A=bb, B=h1 fragment)  — one-time global loads
    const char* bt = reinterpret_cast<const char*>(pk) +
                     (size_t)128 * PK_STEP + (size_t)((g0 + wn) * 16 + oct) * 512 +
                     (size_t)l31 * 16;
#pragma unroll
    for (int c = 0; c < 8; ++c) {
      bf16x8 bfr = __builtin_bit_cast(bf16x8, *reinterpret_cast<const uint4v*>(bt + c * 1024));
#pragma unroll
      for (int ms = 0; ms < 2; ++ms) {
        bf16x8 a = *reinterpret_cast<const bf16x8*>(
            h1bf + (size_t)(mbase + ms * 32 + l31) * HD + c * 16 + oct * 8);
        acc[ms] = __builtin_amdgcn_mfma_f32_32x32x16_bf16(bfr, a, acc[ms], 0, 0, 0);
      }
    }
    // U2 tail (it=129): accT += mfma(A=bb, B=h2u resident)
    const char* bt2 = bt + PK_STEP;
#pragma unroll
    for (int c = 0; c < 8; ++c) {
      bf16x8 bfr = __builtin_bit_cast(bf16x8, *reinterpret_cast<const uint4v*>(bt2 + c * 1024));
#pragma unroll
      for (int ms = 0; ms < 2; ++ms) {
        acc[ms] = __builtin_amdgcn_mfma_f32_32x32x16_bf16(
            bfr, __builtin_bit_cast(bf16x8, h2u[ms][c]), acc[ms], 0, 0, 0);
      }
    }
  }

  // epilogue: transposed regs regroup into aligned f32x4 row-chunks of out.
  // acc[ms][4q+j] -> out[mbase+ms*32+l31][n0w + 8q + 4*oct + j]
  float* my = part + (size_t)ks * PART_ELEMS;
#pragma unroll
  for (int ms = 0; ms < 2; ++ms) {
    float* rowp = my + (size_t)(mbase + ms * 32 + l31) * NOUT + n0w + 4 * oct;
#pragma unroll
    for (int qq = 0; qq < 4; ++qq) {
      f32x4 o;
      o[0] = acc[ms][qq * 4 + 0];
      o[1] = acc[ms][qq * 4 + 1];
      o[2] = acc[ms][qq * 4 + 2];
      o[3] = acc[ms][qq * 4 + 3];
      *reinterpret_cast<f32x4*>(rowp + 8 * qq) = o;
    }
  }
}

// ---------------- reduce: out = P0 + P1 (bias already in P1) ----------------
__global__ void reduce2(const float* __restrict__ part, float* __restrict__ out) {
  int i = blockIdx.x * 256 + threadIdx.x;          // 1,572,864 float4s
  float4 a = reinterpret_cast<const float4*>(part)[i];
  float4 b = reinterpret_cast<const float4*>(part + PART_ELEMS)[i];
  float4 o;
  o.x = a.x + b.x; o.y = a.y + b.y; o.z = a.z + b.z; o.w = a.w + b.w;
  reinterpret_cast<float4*>(out)[i] = o;
}

extern "C" void kernel_launch(void* const* d_in, const int* in_sizes, int n_in,
                              void* d_out, int out_size, void* d_ws, size_t ws_size,
                              hipStream_t stream) {
  const float* nh  = (const float*)d_in[0];   // (16384, 2, 128)
  const float* A   = (const float*)d_in[1];   // (128, 128, 384)
  const float* U1  = (const float*)d_in[2];   // (384, 128)
  const float* U2  = (const float*)d_in[3];   // (384, 128)
  const float* U2b = (const float*)d_in[4];   // (384,)

  char* ws = (char*)d_ws;
  ushort_t* pk   = (ushort_t*)(ws);                 // 130*98304    = 12,779,520 B
  ushort_t* h1bf = (ushort_t*)(ws + 12779520);      // 16384*128*2 =  4,194,304
  ushort_t* h2bf = (ushort_t*)(ws + 16973824);      //               4,194,304
  float*    h1tf = (float*)(ws + 21168128);         // 128*16384*4 =  8,388,608
  float*    part = (float*)(ws + 29556736);         // 2*25,165,824 = 50,331,648  (total ~79.9 MB)

  prep_all<<<dim3(772), 384, 0, stream>>>(A, U1, U2, nh, pk, h1bf, h2bf, h1tf);
  gemm_kernel<<<dim3(768), 512, 0, stream>>>(pk, h1bf, h2bf, h1tf, U2b, part);
  reduce2<<<dim3(6144), 256, 0, stream>>>(part, (float*)d_out);
}